// Round 3
// baseline (204.427 us; speedup 1.0000x reference)
//
#include <hip/hip_runtime.h>

#define GAT_H 12
#define GAT_N 4096
#define GAT_F 64
#define GAT_NW (GAT_N / 64)      // 64 u64 words per adj row
#define LOG2E 1.4426950408889634f

// ---------------------------------------------------------------------------
// Algebra: with q = log2e*(x_i*s_h + x_j*d_h),
//   exp2(lrelu(q)) = max(exp2(q), exp2(0.2q)) = B1(i,h)*max(E1(j,h), rho(i,h)*E2(j,h))
// B1 cancels in softmax. Tables/scratch in static __device__ memory:
//   g_tab[h][j]  = (exp2(log2e*d_h*x_j), exp2(0.2*log2e*d_h*x_j))   [384 KB]
//   g_bits[r][w] = 64-bit adjacency bitmask (bit = lane = j&63)      [2 MB]
//   rho = exp2(-0.8*log2e*x_i*s_h)                                  [SGPR-pinned]
// Inner loop per (i,j,h): mul + max + 2 fma. No transcendentals, no adj
// vector loads (wave-uniform u64 + cndmask). Accumulators = 48/wave with
// launch_bounds(256,3) -> ~168 VGPR budget: no AGPR shuffle (round-1 bug).
// ---------------------------------------------------------------------------

__device__ float2 g_tab[GAT_H * GAT_N];                 // 384 KB
__device__ float  g_sd[2 * GAT_H + 1];                  // s[12], d[12], mean(x)
__device__ unsigned long long g_bits[GAT_N * GAT_NW];   // 2 MB packed adj

__global__ __launch_bounds__(256) void gat_prep(const float* __restrict__ W,
                                                const float* __restrict__ a,
                                                const float* __restrict__ x,
                                                const int* __restrict__ adj) {
    const int b    = blockIdx.x;
    const int tid  = threadIdx.x;
    const int lane = tid & 63;
    const int wave = tid >> 6;

    if (b < GAT_H) {                       // s_h, d_h (wave 0 only)
        if (wave == 0) {
            const float wf = W[b * GAT_F + lane];
            float ps = wf * a[b * 2 * GAT_F + lane];
            float pd = wf * a[b * 2 * GAT_F + GAT_F + lane];
            #pragma unroll
            for (int off = 32; off > 0; off >>= 1) {
                ps += __shfl_xor(ps, off, 64);
                pd += __shfl_xor(pd, off, 64);
            }
            if (lane == 0) { g_sd[b] = ps; g_sd[GAT_H + b] = pd; }
        }
        return;
    }
    if (b == GAT_H) {                      // mean(x) fallback (wave 0 only)
        if (wave == 0) {
            float s = 0.0f;
            #pragma unroll
            for (int j = 0; j < GAT_N / 64; ++j) s += x[j * 64 + lane];
            #pragma unroll
            for (int off = 32; off > 0; off >>= 1) s += __shfl_xor(s, off, 64);
            if (lane == 0) g_sd[2 * GAT_H] = s * (1.0f / GAT_N);
        }
        return;
    }
    if (b < GAT_H + 1 + 48) {              // table: h = bt>>2, 1024-wide chunk
        const int bt    = b - (GAT_H + 1);
        const int h     = bt >> 2;
        const int chunk = bt & 3;
        const float wf  = W[h * GAT_F + lane];
        float pd = wf * a[h * 2 * GAT_F + GAT_F + lane];
        #pragma unroll
        for (int off = 32; off > 0; off >>= 1) pd += __shfl_xor(pd, off, 64);
        const float dl = pd * LOG2E;
        #pragma unroll
        for (int k = 0; k < 4; ++k) {
            const int j   = chunk * 1024 + k * 256 + tid;
            const float t = dl * x[j];
            g_tab[h * GAT_N + j] = make_float2(__builtin_amdgcn_exp2f(t),
                                               __builtin_amdgcn_exp2f(0.2f * t));
        }
        return;
    }

    // adj bit-pack: 512 blocks, 8 rows/block (2 per wave). HBM-bound.
    const int bp  = b - (GAT_H + 1 + 48);
    const int row = bp * 8 + wave * 2;
    #pragma unroll
    for (int rr = 0; rr < 2; ++rr) {
        const int r = row + rr;
        const int* __restrict__ ar = adj + (size_t)r * GAT_N;
        #pragma unroll 4
        for (int it = 0; it < GAT_NW; ++it) {
            const unsigned long long mask = __ballot(ar[it * 64 + lane] > 0);
            if (lane == 0) g_bits[r * GAT_NW + it] = mask;
        }
    }
}

// Main: 4 rows/block, 4 waves = (h-group 0/1 of 6 heads) x (j-half 0/1).
// Per wave-iter (64 j): 6 table float2 loads, 4 wave-uniform u64 bit words,
// 1 LDS x read; ~24 mask VALU + 96 triple VALU.
__global__ __launch_bounds__(256, 3) void gat_main(const float* __restrict__ x,
                                                   const float* __restrict__ W,
                                                   float* __restrict__ out) {
    __shared__ float xs[GAT_N];
    __shared__ float rho_s[4][16];
    __shared__ float part[2][2][4][6][2];   // [jh][hg][row][hh][den,num]
    __shared__ float cbuf[4][GAT_H];

    const int tid  = threadIdx.x;
    const int row0 = blockIdx.x * 4;

    #pragma unroll
    for (int it = 0; it < GAT_N / (256 * 4); ++it)
        ((float4*)xs)[it * 256 + tid] = ((const float4*)x)[it * 256 + tid];
    if (tid < 64) {
        const int r = tid >> 4, hh = tid & 15;
        if (hh < GAT_H)
            rho_s[r][hh] =
                __builtin_amdgcn_exp2f(-0.8f * LOG2E * x[row0 + r] * g_sd[hh]);
    }
    __syncthreads();

    const int lane  = tid & 63;
    const int wave  = tid >> 6;
    const int hg    = wave >> 1;
    const int jh    = wave & 1;
    const int hbase = hg * 6;
    const int jb    = jh * 2048 + lane;

    // rho is wave-uniform -> pin to SGPRs so the per-triple mul reads SGPR.
    float rho[4][6];
    #pragma unroll
    for (int r = 0; r < 4; ++r)
        #pragma unroll
        for (int hh = 0; hh < 6; ++hh)
            rho[r][hh] = __uint_as_float(__builtin_amdgcn_readfirstlane(
                __float_as_uint(rho_s[r][hbase + hh])));

    float den[4][6], num[4][6];
    #pragma unroll
    for (int r = 0; r < 4; ++r)
        #pragma unroll
        for (int hh = 0; hh < 6; ++hh) { den[r][hh] = 0.0f; num[r][hh] = 0.0f; }

    const float2* __restrict__ tb = g_tab + hbase * GAT_N + jb;
    const unsigned long long* __restrict__ bp0 =
        g_bits + (size_t)row0 * GAT_NW + jh * 32;    // word w of row r: bp0[r*64+w]

    float2 E_c[6];
    unsigned long long b_c[4];
    #pragma unroll
    for (int hh = 0; hh < 6; ++hh) E_c[hh] = tb[hh * GAT_N];
    #pragma unroll
    for (int r = 0; r < 4; ++r)    b_c[r]  = bp0[r * GAT_NW];
    float x_c = xs[jb];

    #pragma unroll 1
    for (int e = 0; e < 32; ++e) {
        const int en = (e < 31) ? e + 1 : 31;        // clamped prefetch
        float2 E_n[6];
        unsigned long long b_n[4];
        #pragma unroll
        for (int hh = 0; hh < 6; ++hh) E_n[hh] = tb[hh * GAT_N + en * 64];
        #pragma unroll
        for (int r = 0; r < 4; ++r)    b_n[r]  = bp0[r * GAT_NW + en];
        const float x_n = xs[jb + en * 64];

        float m[4], mxj[4];
        #pragma unroll
        for (int r = 0; r < 4; ++r) {
            const bool nb = (b_c[r] >> lane) & 1ull;
            m[r]   = nb ? 1.0f : 0.0f;
            mxj[r] = nb ? x_c  : 0.0f;
        }
        #pragma unroll
        for (int hh = 0; hh < 6; ++hh) {
            const float e1 = E_c[hh].x, e2 = E_c[hh].y;
            #pragma unroll
            for (int r = 0; r < 4; ++r) {
                const float p = fmaxf(e1, rho[r][hh] * e2);
                den[r][hh] = fmaf(p, m[r],   den[r][hh]);
                num[r][hh] = fmaf(p, mxj[r], num[r][hh]);
            }
        }
        #pragma unroll
        for (int hh = 0; hh < 6; ++hh) E_c[hh] = E_n[hh];
        #pragma unroll
        for (int r = 0; r < 4; ++r)    b_c[r]  = b_n[r];
        x_c = x_n;
    }

    #pragma unroll
    for (int r = 0; r < 4; ++r) {
        #pragma unroll
        for (int hh = 0; hh < 6; ++hh) {
            float d = den[r][hh], n = num[r][hh];
            #pragma unroll
            for (int off = 32; off > 0; off >>= 1) {
                d += __shfl_xor(d, off, 64);
                n += __shfl_xor(n, off, 64);
            }
            if (lane == 0) {
                part[jh][hg][r][hh][0] = d;
                part[jh][hg][r][hh][1] = n;
            }
        }
    }
    __syncthreads();

    if (tid < 64) {
        const int r = tid >> 4, h = tid & 15;
        if (h < GAT_H) {
            const int g  = (h >= 6) ? 1 : 0;
            const int hh = h - 6 * g;
            const float dsum = part[0][g][r][hh][0] + part[1][g][r][hh][0];
            const float nsum = part[0][g][r][hh][1] + part[1][g][r][hh][1];
            cbuf[r][h] = dsum > 0.0f ? nsum / dsum : g_sd[2 * GAT_H];
        }
    }
    __syncthreads();

    #pragma unroll
    for (int r = 0; r < 4; ++r) {
        const size_t base = (size_t)(row0 + r) * (GAT_H * GAT_F);
        #pragma unroll
        for (int k = 0; k < 3; ++k) {
            const int pos = k * 256 + tid;
            out[base + pos] = cbuf[r][pos >> 6] * W[pos];
        }
    }
}

extern "C" void kernel_launch(void* const* d_in, const int* in_sizes, int n_in,
                              void* d_out, int out_size, void* d_ws, size_t ws_size,
                              hipStream_t stream) {
    const float* x   = (const float*)d_in[0];
    const int*   adj = (const int*)d_in[1];
    const float* W   = (const float*)d_in[2];
    const float* a   = (const float*)d_in[3];
    float* out = (float*)d_out;
    (void)d_ws; (void)ws_size;   // all scratch is static __device__ memory

    gat_prep<<<GAT_H + 1 + 48 + 512, 256, 0, stream>>>(W, a, x, adj);
    gat_main<<<GAT_N / 4, 256, 0, stream>>>(x, W, out);
}

// Round 4
// 133.222 us; speedup vs baseline: 1.5345x; 1.5345x over previous
//
#include <hip/hip_runtime.h>

#define GAT_H 12
#define GAT_N 4096
#define GAT_F 64
#define LOG2E 1.4426950408889634f

// ---------------------------------------------------------------------------
// Algebra: with q = log2e*(x_i*s_h + x_j*d_h),
//   exp2(lrelu(q)) = max(exp2(q), exp2(0.2q)) = B1(i,h)*max(E1(j,h), rho(i,h)*E2(j,h))
// B1 cancels in softmax. Only E2 = exp2(0.2*log2e*d_h*x_j) is tabulated
// (192 KB, L2-resident); E1 = E2^5 (3 muls, shared across the 4 rows).
// rho = exp2(-0.8*log2e*x_i*s_h) is SGPR-pinned. adj is read directly as
// int4 (adj in {0,1} -> mask via v_cvt_f32_i32 + mul). Layout: 4 j per lane
// (vector loads), 256 j per wave-iter -> 11 loads / 256 elements.
// Inner loop per (i,j,h): mul + max + 2 fma (+ amortized E1/mask ops).
// ---------------------------------------------------------------------------

__device__ float g_tab2[GAT_H * GAT_N];   // 192 KB: E2 table
__device__ float g_sd[2 * GAT_H + 1];     // s[12], d[12], mean(x)

__global__ __launch_bounds__(256) void gat_prep(const float* __restrict__ W,
                                                const float* __restrict__ a,
                                                const float* __restrict__ x) {
    const int b    = blockIdx.x;
    const int tid  = threadIdx.x;
    const int lane = tid & 63;
    const int wave = tid >> 6;

    if (b < GAT_H) {                       // s_h, d_h (wave 0 only)
        if (wave == 0) {
            const float wf = W[b * GAT_F + lane];
            float ps = wf * a[b * 2 * GAT_F + lane];
            float pd = wf * a[b * 2 * GAT_F + GAT_F + lane];
            #pragma unroll
            for (int off = 32; off > 0; off >>= 1) {
                ps += __shfl_xor(ps, off, 64);
                pd += __shfl_xor(pd, off, 64);
            }
            if (lane == 0) { g_sd[b] = ps; g_sd[GAT_H + b] = pd; }
        }
        return;
    }
    if (b == GAT_H) {                      // mean(x) fallback (wave 0 only)
        if (wave == 0) {
            float s = 0.0f;
            #pragma unroll
            for (int j = 0; j < GAT_N / 64; ++j) s += x[j * 64 + lane];
            #pragma unroll
            for (int off = 32; off > 0; off >>= 1) s += __shfl_xor(s, off, 64);
            if (lane == 0) g_sd[2 * GAT_H] = s * (1.0f / GAT_N);
        }
        return;
    }

    // Table blocks: bt in [0,48): h = bt>>2, 1024-wide j-chunk = bt&3.
    const int bt    = b - (GAT_H + 1);
    const int h     = bt >> 2;
    const int chunk = bt & 3;
    const float wf  = W[h * GAT_F + lane];
    float pd = wf * a[h * 2 * GAT_F + GAT_F + lane];
    #pragma unroll
    for (int off = 32; off > 0; off >>= 1) pd += __shfl_xor(pd, off, 64);
    const float dl5 = 0.2f * pd * LOG2E;
    #pragma unroll
    for (int k = 0; k < 4; ++k) {
        const int j = chunk * 1024 + k * 256 + tid;
        g_tab2[h * GAT_N + j] = __builtin_amdgcn_exp2f(dl5 * x[j]);
    }
}

// Main: 4 rows/block, 4 waves = (h-group 0/1 of 6 heads) x (j-half 0/1).
// Per wave-iter (256 j): 4 int4 adj + 6 float4 table + 1 LDS b128;
// ~32 mask VALU + 72 E1-recon + 384 triple VALU.
__global__ __launch_bounds__(256, 3) void gat_main(const float* __restrict__ x,
                                                   const int* __restrict__ adj,
                                                   const float* __restrict__ W,
                                                   float* __restrict__ out) {
    __shared__ float xs[GAT_N];
    __shared__ float rho_s[4][16];
    __shared__ float part[2][2][4][6][2];   // [jh][hg][row][hh][den,num]
    __shared__ float cbuf[4][GAT_H];

    const int tid  = threadIdx.x;
    const int row0 = blockIdx.x * 4;

    #pragma unroll
    for (int it = 0; it < GAT_N / (256 * 4); ++it)
        ((float4*)xs)[it * 256 + tid] = ((const float4*)x)[it * 256 + tid];
    if (tid < 64) {
        const int r = tid >> 4, hh = tid & 15;
        if (hh < GAT_H)
            rho_s[r][hh] =
                __builtin_amdgcn_exp2f(-0.8f * LOG2E * x[row0 + r] * g_sd[hh]);
    }
    __syncthreads();

    const int lane  = tid & 63;
    const int wave  = tid >> 6;
    const int hg    = wave >> 1;
    const int jh    = wave & 1;
    const int hbase = hg * 6;

    // rho is wave-uniform -> pin to SGPRs so the per-triple mul reads SGPR.
    float rho[4][6];
    #pragma unroll
    for (int r = 0; r < 4; ++r)
        #pragma unroll
        for (int hh = 0; hh < 6; ++hh)
            rho[r][hh] = __uint_as_float(__builtin_amdgcn_readfirstlane(
                __float_as_uint(rho_s[r][hbase + hh])));

    float den[4][6], num[4][6];
    #pragma unroll
    for (int r = 0; r < 4; ++r)
        #pragma unroll
        for (int hh = 0; hh < 6; ++hh) { den[r][hh] = 0.0f; num[r][hh] = 0.0f; }

    // 4 j per lane: j = jh*2048 + it*256 + 4*lane + e
    const int4*   __restrict__ a4p = (const int4*)(adj + (size_t)row0 * GAT_N + jh * 2048);
    const float4* __restrict__ t4  = (const float4*)(g_tab2 + hbase * GAT_N + jh * 2048);
    const float4* __restrict__ x4  = (const float4*)(xs + jh * 2048);

    int4   ac[4];
    float4 xc;
    #pragma unroll
    for (int r = 0; r < 4; ++r) ac[r] = a4p[r * (GAT_N / 4) + lane];
    xc = x4[lane];

    #pragma unroll 1
    for (int it = 0; it < 8; ++it) {
        const int nxt = (it < 7 ? it + 1 : 7) * 64 + lane;   // clamped prefetch
        int4 an[4];
        #pragma unroll
        for (int r = 0; r < 4; ++r) an[r] = a4p[r * (GAT_N / 4) + nxt];
        const float4 xn = x4[nxt];

        // masks: am = (float)adj (adj in {0,1}), axj = am * x_j
        float am[4][4], axj[4][4];
        #pragma unroll
        for (int r = 0; r < 4; ++r) {
            const int* ai = (const int*)&ac[r];
            const float* xv = (const float*)&xc;
            #pragma unroll
            for (int e = 0; e < 4; ++e) {
                am[r][e]  = (float)ai[e];
                axj[r][e] = am[r][e] * xv[e];
            }
        }

        #pragma unroll
        for (int hh = 0; hh < 6; ++hh) {
            const float4 e2v = t4[hh * (GAT_N / 4) + it * 64 + lane];
            const float* e2 = (const float*)&e2v;
            float e1[4];
            #pragma unroll
            for (int e = 0; e < 4; ++e) {
                const float sq = e2[e] * e2[e];
                e1[e] = sq * sq * e2[e];                    // E1 = E2^5
            }
            #pragma unroll
            for (int e = 0; e < 4; ++e) {
                #pragma unroll
                for (int r = 0; r < 4; ++r) {
                    const float p = fmaxf(e1[e], rho[r][hh] * e2[e]);
                    den[r][hh] = fmaf(p, am[r][e],  den[r][hh]);
                    num[r][hh] = fmaf(p, axj[r][e], num[r][hh]);
                }
            }
        }
        #pragma unroll
        for (int r = 0; r < 4; ++r) ac[r] = an[r];
        xc = xn;
    }

    #pragma unroll
    for (int r = 0; r < 4; ++r) {
        #pragma unroll
        for (int hh = 0; hh < 6; ++hh) {
            float d = den[r][hh], n = num[r][hh];
            #pragma unroll
            for (int off = 32; off > 0; off >>= 1) {
                d += __shfl_xor(d, off, 64);
                n += __shfl_xor(n, off, 64);
            }
            if (lane == 0) {
                part[jh][hg][r][hh][0] = d;
                part[jh][hg][r][hh][1] = n;
            }
        }
    }
    __syncthreads();

    if (tid < 64) {
        const int r = tid >> 4, h = tid & 15;
        if (h < GAT_H) {
            const int g  = (h >= 6) ? 1 : 0;
            const int hh = h - 6 * g;
            const float dsum = part[0][g][r][hh][0] + part[1][g][r][hh][0];
            const float nsum = part[0][g][r][hh][1] + part[1][g][r][hh][1];
            cbuf[r][h] = dsum > 0.0f ? nsum / dsum : g_sd[2 * GAT_H];
        }
    }
    __syncthreads();

    #pragma unroll
    for (int r = 0; r < 4; ++r) {
        const size_t base = (size_t)(row0 + r) * (GAT_H * GAT_F);
        #pragma unroll
        for (int k = 0; k < 3; ++k) {
            const int pos = k * 256 + tid;
            out[base + pos] = cbuf[r][pos >> 6] * W[pos];
        }
    }
}

extern "C" void kernel_launch(void* const* d_in, const int* in_sizes, int n_in,
                              void* d_out, int out_size, void* d_ws, size_t ws_size,
                              hipStream_t stream) {
    const float* x   = (const float*)d_in[0];
    const int*   adj = (const int*)d_in[1];
    const float* W   = (const float*)d_in[2];
    const float* a   = (const float*)d_in[3];
    float* out = (float*)d_out;
    (void)d_ws; (void)ws_size;   // all scratch is static __device__ memory

    gat_prep<<<GAT_H + 1 + 48, 256, 0, stream>>>(W, a, x);
    gat_main<<<GAT_N / 4, 256, 0, stream>>>(x, adj, W, out);
}